// Round 1
// 2169.081 us; speedup vs baseline: 1.4563x; 1.4563x over previous
//
#include <hip/hip_runtime.h>

// ---------------------------------------------------------------------------
// TopK SAE: z = relu(x @ W_enc^T); z_sparse = topk(z, 32); x_hat = z_sparse @ W_dec^T
// N=8192, D_IN=1024, D_HID=16384, K=32
//
// Pipeline:
//   1. split x, W_enc (fp32) -> hi/lo fp16 pairs, scaled by 256 (subnormal guard)
//   2. fp16x2 MFMA GEMM (3 products: x1w1 + x1w2 + x2w1) -> fp32-accurate z
//   3. zero-fill z_sparse region + counter
//   4. exact per-row top-32 via histogram radix-select:
//      row kept in registers (64 f32/thread), 2048-bin LDS histogram of top-11
//      float bits, suffix-scan to find the 32nd-value bin, compact candidates
//      (~100-200), rank by exact (value desc, index asc) order -> same
//      selection as lax.top_k, bit-identical to the previous serial version.
//      (replaces the 32-round serial merge that was VALU-bound at 94% with
//      2.4e8 LDS bank conflicts and 15x over the memory roofline)
//   5. transpose W_dec -> W_dec^T in ws
//   6. sparse decode: x_hat[row] = sum_j v_j * WdT[idx_j][:]
//   7. active = count(vals > 0)/N
// ---------------------------------------------------------------------------

#define N_ROWS   8192
#define D_IN     1024
#define D_HID    16384
#define TOPK     32

typedef _Float16 half8  __attribute__((ext_vector_type(8)));
typedef _Float16 half4v __attribute__((ext_vector_type(4)));
typedef float    floatx4 __attribute__((ext_vector_type(4)));

// ---- workspace layout (bytes). W1/W2 overlap WDT: transpose runs after gemm.
#define WS_W1    ((size_t)0)
#define WS_W2    ((size_t)33554432)
#define WS_WDT   ((size_t)0)            // 67,108,864 B, reuses W1+W2 after gemm
#define WS_X1    ((size_t)67108864)
#define WS_X2    ((size_t)83886080)
#define WS_TOPV  ((size_t)100663296)
#define WS_TOPI  ((size_t)101711872)
#define WS_CNT   ((size_t)102760448)

// ---- output layout (floats)
#define OFF_XHAT ((size_t)0)
#define OFF_ZS   ((size_t)8388608)
#define OFF_Z    ((size_t)142606336)
#define OFF_ACT  ((size_t)276824064)

// ---------------------------------------------------------------------------
__device__ __forceinline__ void gload16(void* lds, const void* gptr) {
  __builtin_amdgcn_global_load_lds(
      (const __attribute__((address_space(1))) unsigned int*)gptr,
      (__attribute__((address_space(3))) unsigned int*)lds,
      16, 0, 0);
}

// ---------------------------------------------------------------------------
// 1. split fp32 -> (hi, lo) fp16, scaled by 256
__global__ __launch_bounds__(256) void split_fp16(
    const float4* __restrict__ in, half4v* __restrict__ o1,
    half4v* __restrict__ o2, int n4)
{
  int i = blockIdx.x * 256 + threadIdx.x;
  int stride = gridDim.x * 256;
  for (; i < n4; i += stride) {
    float4 v = in[i];
    float a0 = v.x * 256.0f, a1 = v.y * 256.0f, a2 = v.z * 256.0f, a3 = v.w * 256.0f;
    half4v h1, h2;
    h1[0] = (_Float16)a0; h1[1] = (_Float16)a1; h1[2] = (_Float16)a2; h1[3] = (_Float16)a3;
    h2[0] = (_Float16)(a0 - (float)h1[0]);
    h2[1] = (_Float16)(a1 - (float)h1[1]);
    h2[2] = (_Float16)(a2 - (float)h1[2]);
    h2[3] = (_Float16)(a3 - (float)h1[3]);
    o1[i] = h1; o2[i] = h2;
  }
}

// ---------------------------------------------------------------------------
// 2. fp16x2 GEMM: z[m][n] = relu( (x@W^T)[m][n] ), fp32-accurate.
//    BM=BN=128, BK=32, 256 threads (4 waves), wave -> 64x64 (4x4 of 16x16 MFMA).
__global__ __launch_bounds__(256, 2) void gemm_enc(
    const _Float16* __restrict__ x1, const _Float16* __restrict__ x2,
    const _Float16* __restrict__ w1, const _Float16* __restrict__ w2,
    float* __restrict__ zout)
{
  __shared__ alignas(16) _Float16 sA1[128 * 32];
  __shared__ alignas(16) _Float16 sA2[128 * 32];
  __shared__ alignas(16) _Float16 sB1[128 * 32];
  __shared__ alignas(16) _Float16 sB2[128 * 32];

  // 8x8 block-cluster swizzle for L2 locality. grid = 8192 = (64 m) x (128 n)
  int bid    = blockIdx.x;
  int cid    = bid >> 6;          // 128 clusters (8x16)
  int within = bid & 63;
  int cm     = cid & 7;
  int cn     = cid >> 3;
  int mblk   = cm * 8 + (within & 7);
  int nblk   = cn * 8 + (within >> 3);

  int tid  = threadIdx.x;
  int wid  = tid >> 6, lane = tid & 63;
  int wm   = wid >> 1, wn = wid & 1;

  // staging geometry: wave wid covers chunks {2*wid, 2*wid+1} of each tile;
  // chunk = 16 rows x 64B; lane i -> row c*16 + i/4, k-halves (i%4)*8.
  int c0    = wid * 2;
  int srow0 = lane >> 2;
  int skh   = (lane & 3) * 8;

  const size_t arow0 = (size_t)mblk * 128;
  const size_t brow0 = (size_t)nblk * 128;

  floatx4 acc[4][4];
#pragma unroll
  for (int t = 0; t < 4; t++)
#pragma unroll
    for (int u = 0; u < 4; u++) acc[t][u] = (floatx4)0.0f;

  int arow = wm * 64 + (lane & 15);
  int brow = wn * 64 + (lane & 15);
  int koff = (lane >> 4) * 8;

  for (int kb = 0; kb < D_IN / 32; ++kb) {
    __syncthreads();
#pragma unroll
    for (int rep = 0; rep < 2; ++rep) {
      int c = c0 + rep;
      int r = c * 16 + srow0;
      size_t ga = (arow0 + r) * D_IN + kb * 32 + skh;
      size_t gb = (brow0 + r) * D_IN + kb * 32 + skh;
      gload16((char*)sA1 + c * 1024, x1 + ga);
      gload16((char*)sA2 + c * 1024, x2 + ga);
      gload16((char*)sB1 + c * 1024, w1 + gb);
      gload16((char*)sB2 + c * 1024, w2 + gb);
    }
    __syncthreads();

    half8 a1f[4], a2f[4], b1f[4], b2f[4];
#pragma unroll
    for (int t = 0; t < 4; t++) {
      a1f[t] = *(const half8*)&sA1[(arow + t * 16) * 32 + koff];
      a2f[t] = *(const half8*)&sA2[(arow + t * 16) * 32 + koff];
      b1f[t] = *(const half8*)&sB1[(brow + t * 16) * 32 + koff];
      b2f[t] = *(const half8*)&sB2[(brow + t * 16) * 32 + koff];
    }
#pragma unroll
    for (int t = 0; t < 4; t++)
#pragma unroll
      for (int u = 0; u < 4; u++) {
        acc[t][u] = __builtin_amdgcn_mfma_f32_16x16x32_f16(a1f[t], b1f[u], acc[t][u], 0, 0, 0);
        acc[t][u] = __builtin_amdgcn_mfma_f32_16x16x32_f16(a1f[t], b2f[u], acc[t][u], 0, 0, 0);
        acc[t][u] = __builtin_amdgcn_mfma_f32_16x16x32_f16(a2f[t], b1f[u], acc[t][u], 0, 0, 0);
      }
  }

  // epilogue: C row = (lane>>4)*4 + reg, col = lane&15 (m89-verified layout)
  int crow = (lane >> 4) * 4;
  int ccol = lane & 15;
  const float s = 1.0f / 65536.0f;   // undo 256*256 input scaling
#pragma unroll
  for (int t = 0; t < 4; t++) {
    size_t grow = (size_t)mblk * 128 + wm * 64 + t * 16 + crow;
#pragma unroll
    for (int u = 0; u < 4; u++) {
      size_t gcol = (size_t)nblk * 128 + wn * 64 + u * 16 + ccol;
#pragma unroll
      for (int r = 0; r < 4; r++) {
        float v = acc[t][u][r] * s;
        v = v > 0.0f ? v : 0.0f;
        zout[(grow + r) * D_HID + gcol] = v;
      }
    }
  }
}

// ---------------------------------------------------------------------------
// 3. zero z_sparse + counter
__global__ __launch_bounds__(256) void zerofill(
    float4* __restrict__ p, unsigned n4, unsigned* __restrict__ cnt)
{
  unsigned i = blockIdx.x * 256 + threadIdx.x;
  if (i == 0) *cnt = 0u;
  float4 z = make_float4(0.f, 0.f, 0.f, 0.f);
  for (; i < n4; i += gridDim.x * 256) p[i] = z;
}

// ---------------------------------------------------------------------------
// 4. exact per-row top-32 via histogram radix-select.
//    Selection order identical to lax.top_k: value desc, index asc on ties.
#define BETTER(v1, i1, v2, i2) ((v1) > (v2) || ((v1) == (v2) && (i1) < (i2)))
#define NBINS 2048
#define CAND_CAP 1024

__global__ __launch_bounds__(256) void topk_rows(
    const float* __restrict__ z, float* __restrict__ z_sparse,
    float* __restrict__ topv, int* __restrict__ topi,
    unsigned* __restrict__ counter)
{
  int row = blockIdx.x;
  int tid = threadIdx.x;
  const float* zr = z + (size_t)row * D_HID;

  __shared__ unsigned hist[NBINS];     // 8 KB
  __shared__ unsigned csum[256];       // 1 KB  (chunk suffix sums)
  __shared__ float    cv[CAND_CAP];    // 4 KB
  __shared__ int      ci[CAND_CAP];    // 4 KB
  __shared__ int      sB;
  __shared__ unsigned ccnt;
  __shared__ unsigned blk_pos;

#pragma unroll
  for (int i = tid; i < NBINS; i += 256) hist[i] = 0u;
  if (tid == 0) { ccnt = 0u; blk_pos = 0u; }
  __syncthreads();

  // ---- pass 1: load row into registers (64 f32/thread) + histogram top-11 bits.
  // z >= 0 post-relu, so the uint bit pattern is monotone in value.
  // Zeros (~half the row) are batched into one atomic per thread to avoid
  // same-address LDS atomic serialization.
  float4 vreg[16];
  unsigned lo = 0u;
#pragma unroll
  for (int s = 0; s < 16; ++s) {
    vreg[s] = *(const float4*)&zr[s * 1024 + tid * 4];
  }
#pragma unroll
  for (int s = 0; s < 16; ++s) {
    float vs[4] = {vreg[s].x, vreg[s].y, vreg[s].z, vreg[s].w};
#pragma unroll
    for (int c = 0; c < 4; ++c) {
      unsigned b = __float_as_uint(vs[c]) >> 21;
      if (b == 0u) ++lo;
      else atomicAdd(&hist[b], 1u);
    }
  }
  if (lo) atomicAdd(&hist[0], lo);
  __syncthreads();

  // ---- find crossing bin B: highest bin with (count of elements in bins >= B) >= 32.
  // Thread t owns bins [8t, 8t+8). Chunk sum, then Hillis-Steele suffix scan.
  unsigned csl = 0u;
#pragma unroll
  for (int j = 0; j < 8; ++j) csl += hist[tid * 8 + j];
  csum[tid] = csl;
  __syncthreads();
#pragma unroll
  for (int off = 1; off < 256; off <<= 1) {
    unsigned v = (tid + off < 256) ? csum[tid + off] : 0u;
    __syncthreads();
    csum[tid] += v;
    __syncthreads();
  }
  {
    unsigned above = (tid < 255) ? csum[tid + 1] : 0u;   // strictly above my chunk
    unsigned run = above;
#pragma unroll
    for (int j = 7; j >= 0; --j) {
      int bin = tid * 8 + j;
      unsigned h = hist[bin];
      // first (highest) bin where cumulative-from-top crosses 32
      if (run < (unsigned)TOPK && run + h >= (unsigned)TOPK) sB = bin;
      run += h;
    }
  }
  __syncthreads();
  // total count is always D_HID >= 32, so sB is set. sB==0 cannot occur for
  // this data (thousands of positives/row); clamp for bounded runtime anyway.
  unsigned B = (unsigned)(sB > 0 ? sB : 1);
  // ---- pass 2: compact candidates (bin >= B) from registers into LDS.
#pragma unroll
  for (int s = 0; s < 16; ++s) {
    float vs[4] = {vreg[s].x, vreg[s].y, vreg[s].z, vreg[s].w};
#pragma unroll
    for (int c = 0; c < 4; ++c) {
      unsigned u = __float_as_uint(vs[c]);
      if ((u >> 21) >= B) {
        unsigned pos = atomicAdd(&ccnt, 1u);
        if (pos < CAND_CAP) { cv[pos] = vs[c]; ci[pos] = s * 1024 + tid * 4 + c; }
      }
    }
  }
  __syncthreads();

  // ---- rank-select: rank(p) = #{q BETTER than p}; rank < 32 -> winner at
  // its final sorted position. Total order (distinct indices) => exact.
  int C = (int)(ccnt < (unsigned)CAND_CAP ? ccnt : (unsigned)CAND_CAP);
  for (int p = tid; p < C; p += 256) {
    float v = cv[p]; int ix = ci[p];
    int rank = 0;
    for (int q = 0; q < C; ++q) {
      if (BETTER(cv[q], ci[q], v, ix)) ++rank;   // broadcast LDS reads
    }
    if (rank < TOPK) {
      topv[row * TOPK + rank] = v;
      topi[row * TOPK + rank] = ix;
      z_sparse[(size_t)row * D_HID + ix] = v;
      if (v > 0.0f) atomicAdd(&blk_pos, 1u);
    }
  }
  __syncthreads();
  if (tid == 0) atomicAdd(counter, blk_pos);
}

// ---------------------------------------------------------------------------
// 5. transpose W_dec [1024][16384] -> WdT [16384][1024]
__global__ __launch_bounds__(256) void transpose_wdec(
    const float* __restrict__ wd, float* __restrict__ wdt)
{
  __shared__ float t[32][33];
  int bx = blockIdx.x;            // D_HID/32 = 512
  int by = blockIdx.y;            // D_IN/32  = 32
  int tx = threadIdx.x & 31, ty = threadIdx.x >> 5;   // ty 0..7
#pragma unroll
  for (int r = 0; r < 4; r++) {
    int c = by * 32 + ty + r * 8;       // D_IN index
    int j = bx * 32 + tx;               // D_HID index
    t[ty + r * 8][tx] = wd[(size_t)c * D_HID + j];
  }
  __syncthreads();
#pragma unroll
  for (int r = 0; r < 4; r++) {
    int j = bx * 32 + ty + r * 8;       // D_HID index
    int c = by * 32 + tx;               // D_IN index
    wdt[(size_t)j * D_IN + c] = t[tx][ty + r * 8];
  }
}

// ---------------------------------------------------------------------------
// 6. sparse decode: x_hat[row][:] = sum_j topv[j] * WdT[topi[j]][:]
__global__ __launch_bounds__(256) void decode(
    const float* __restrict__ topv, const int* __restrict__ topi,
    const float* __restrict__ wdt, float* __restrict__ xhat)
{
  int row = blockIdx.x;
  int tid = threadIdx.x;
  __shared__ float vv[TOPK]; __shared__ int ii[TOPK];
  if (tid < TOPK) { vv[tid] = topv[row * TOPK + tid]; ii[tid] = topi[row * TOPK + tid]; }
  __syncthreads();
  float ax = 0.f, ay = 0.f, az = 0.f, aw = 0.f;
  int c = tid * 4;
#pragma unroll 4
  for (int j = 0; j < TOPK; j++) {
    float v = vv[j];
    float4 w = *(const float4*)&wdt[(size_t)ii[j] * D_IN + c];
    ax += v * w.x; ay += v * w.y; az += v * w.z; aw += v * w.w;
  }
  float4 o = make_float4(ax, ay, az, aw);
  *(float4*)&xhat[(size_t)row * D_IN + c] = o;
}

// ---------------------------------------------------------------------------
// 7. active scalar
__global__ void finalize_active(const unsigned* __restrict__ cnt, float* __restrict__ out)
{
  if (threadIdx.x == 0) out[0] = (float)(*cnt) * (1.0f / (float)N_ROWS);
}

// ---------------------------------------------------------------------------
extern "C" void kernel_launch(void* const* d_in, const int* in_sizes, int n_in,
                              void* d_out, int out_size, void* d_ws, size_t ws_size,
                              hipStream_t stream)
{
  const float* x     = (const float*)d_in[0];
  const float* W_enc = (const float*)d_in[1];
  const float* W_dec = (const float*)d_in[2];
  float* out = (float*)d_out;
  char*  ws  = (char*)d_ws;

  _Float16* x1 = (_Float16*)(ws + WS_X1);
  _Float16* x2 = (_Float16*)(ws + WS_X2);
  _Float16* w1 = (_Float16*)(ws + WS_W1);
  _Float16* w2 = (_Float16*)(ws + WS_W2);
  float*    wdt  = (float*)(ws + WS_WDT);
  float*    topv = (float*)(ws + WS_TOPV);
  int*      topi = (int*)(ws + WS_TOPI);
  unsigned* cnt  = (unsigned*)(ws + WS_CNT);

  float* xhat = out + OFF_XHAT;
  float* zsp  = out + OFF_ZS;
  float* z    = out + OFF_Z;
  float* act  = out + OFF_ACT;

  split_fp16<<<1024, 256, 0, stream>>>((const float4*)x, (half4v*)x1, (half4v*)x2,
                                       N_ROWS * D_IN / 4);
  split_fp16<<<2048, 256, 0, stream>>>((const float4*)W_enc, (half4v*)w1, (half4v*)w2,
                                       D_HID * D_IN / 4);
  gemm_enc<<<8192, 256, 0, stream>>>(x1, x2, w1, w2, z);
  zerofill<<<4096, 256, 0, stream>>>((float4*)zsp, (unsigned)(N_ROWS * (D_HID / 4)), cnt);
  topk_rows<<<N_ROWS, 256, 0, stream>>>(z, zsp, topv, topi, cnt);
  transpose_wdec<<<dim3(512, 32), 256, 0, stream>>>(W_dec, wdt);   // after gemm: overlaps w1/w2
  decode<<<N_ROWS, 256, 0, stream>>>(topv, topi, wdt, xhat);
  finalize_active<<<1, 64, 0, stream>>>(cnt, act);
}